// Round 3
// baseline (837.231 us; speedup 1.0000x reference)
//
#include <hip/hip_runtime.h>
#include <cstdint>

typedef __bf16 bf16;
typedef __bf16 bf16x8 __attribute__((ext_vector_type(8)));
typedef __bf16 bf16x4 __attribute__((ext_vector_type(4)));
typedef float f32x4 __attribute__((ext_vector_type(4)));

#define DEVINL __device__ __forceinline__

namespace {
constexpr int DIM = 1024, HEADS = 8, HD = 128, HALF = 64;
constexpr int SQ = 512;
constexpr int SK = 31290;
constexpr int SKP = 31360;               // 245*128
constexpr int NT = SKP / 64;             // 490 kv tiles
constexpr int NSPLIT = 32;
constexpr int TPS = (NT + NSPLIT - 1) / NSPLIT;  // 16

// workspace layout (bytes). Opart ALIASES [memb|xb|Wkv] which are dead by attn time.
constexpr long OFF_MEMB = 0;
constexpr long OFF_XB   = OFF_MEMB + (long)SKP * DIM * 2;
constexpr long OFF_WKV  = OFF_XB + (long)SQ * DIM * 2;
constexpr long OFF_WQ   = OFF_WKV + 2048L * DIM * 2;
constexpr long OFF_WO   = OFF_WQ + (long)DIM * DIM * 2;
constexpr long OFF_BKV  = OFF_WO + (long)DIM * DIM * 2;
constexpr long OFF_KPRE = OFF_BKV + 2048L * 4;
constexpr long OFF_VT   = OFF_KPRE + (long)SKP * DIM * 2;
constexpr long OFF_QPRE = OFF_VT + (long)DIM * SKP * 2;
constexpr long OFF_QR   = OFF_QPRE + (long)SQ * DIM * 4;
constexpr long OFF_BIAS = OFF_QR + (long)SQ * DIM * 2;
constexpr long OFF_ML   = OFF_BIAS + (long)SKP * 4;
constexpr long OFF_AO   = OFF_ML + (long)NSPLIT * HEADS * SQ * 2 * 4;
constexpr long OFF_OP   = OFF_MEMB;      // 67.1MB, < OFF_KPRE (73.7MB): only dead bufs
}

DEVINL void gl_lds16(const void* g, void* l) {
  __builtin_amdgcn_global_load_lds(
      (__attribute__((address_space(1))) void*)(void*)g,
      (__attribute__((address_space(3))) void*)l, 16, 0, 0);
}

// ---------------- converts ----------------

__global__ __launch_bounds__(256) void k_cvt_mem(const float* __restrict__ mem,
                                                 bf16* __restrict__ memb) {
  long i = (long)blockIdx.x * 256 + threadIdx.x;
  long e = i * 8;
  if (e >= (long)SKP * DIM) return;
  int row = (int)(e >> 10);
  bf16x8 o;
  if (row < SK) {
    float4 a = *(const float4*)(mem + e);
    float4 b = *(const float4*)(mem + e + 4);
    o[0] = (bf16)a.x; o[1] = (bf16)a.y; o[2] = (bf16)a.z; o[3] = (bf16)a.w;
    o[4] = (bf16)b.x; o[5] = (bf16)b.y; o[6] = (bf16)b.z; o[7] = (bf16)b.w;
  } else {
    #pragma unroll
    for (int j = 0; j < 8; ++j) o[j] = (bf16)0.0f;
  }
  *(bf16x8*)(memb + e) = o;
}

__global__ __launch_bounds__(256) void k_cvt(const float* __restrict__ s,
                                             bf16* __restrict__ d, long n8) {
  long i = (long)blockIdx.x * 256 + threadIdx.x;
  if (i >= n8) return;
  long e = i * 8;
  float4 a = *(const float4*)(s + e);
  float4 b = *(const float4*)(s + e + 4);
  bf16x8 o;
  o[0] = (bf16)a.x; o[1] = (bf16)a.y; o[2] = (bf16)a.z; o[3] = (bf16)a.w;
  o[4] = (bf16)b.x; o[5] = (bf16)b.y; o[6] = (bf16)b.z; o[7] = (bf16)b.w;
  *(bf16x8*)(d + e) = o;
}

__global__ __launch_bounds__(256) void k_build_wkv(const float* __restrict__ Wk,
    const float* __restrict__ Wv, const float* __restrict__ bk,
    const float* __restrict__ bv, bf16* __restrict__ WB, float* __restrict__ bKV) {
  long i = (long)blockIdx.x * 256 + threadIdx.x;
  long e = i * 8;
  if (e < 2048L * 1024) {
    int n = (int)(e >> 10);
    const float* src = (n < 1024) ? (Wk + e) : (Wv + e - 1024L * 1024);
    float4 a = *(const float4*)(src);
    float4 b = *(const float4*)(src + 4);
    bf16x8 o;
    o[0] = (bf16)a.x; o[1] = (bf16)a.y; o[2] = (bf16)a.z; o[3] = (bf16)a.w;
    o[4] = (bf16)b.x; o[5] = (bf16)b.y; o[6] = (bf16)b.z; o[7] = (bf16)b.w;
    *(bf16x8*)(WB + e) = o;
  }
  if (i < 2048) bKV[i] = (i < 1024) ? bk[i] : bv[i - 1024];
}

__global__ __launch_bounds__(256) void k_bias(const int* __restrict__ mask,
                                              float* __restrict__ biasA) {
  int k = blockIdx.x * 256 + threadIdx.x;
  if (k < SKP) biasA[k] = (k < SK && mask[k] != 0) ? 0.0f : -1e30f;
}

// ---------------- GEMM: C = A(MxK) * B(NxK)^T + bias ----------------
// 128x128 tile, BK=64, 256 threads. XCD-chunked block swizzle for A/B L2 reuse.

template<int MODE>
__global__ __launch_bounds__(256, 2)
void k_gemm(const bf16* __restrict__ A, const bf16* __restrict__ B,
            const float* __restrict__ bias, int Mtiles, int Ntiles,
            float* __restrict__ outF, int ldF,
            bf16* __restrict__ outK, bf16* __restrict__ outVT) {
  constexpr int K = 1024;
  __shared__ char lds[32768];
  char* ldsA = lds;
  char* ldsB = lds + 16384;
  int tid = threadIdx.x;
  int w = tid >> 6, lane = tid & 63;
  int cpx = gridDim.x >> 3;                       // grids are %8==0
  int bid = (blockIdx.x & 7) * cpx + (blockIdx.x >> 3);
  int mt = bid / Ntiles, nt = bid % Ntiles;
  int m0 = mt * 128, n0 = nt * 128;
  int wm = w >> 1, wn = w & 1;
  int cl = lane & 15, rg = lane >> 4;

  f32x4 acc[4][4] = {};

  int rowi = lane >> 3, g = lane & 7;
  for (int kt = 0; kt < K / 64; ++kt) {
    #pragma unroll
    for (int j = 0; j < 4; ++j) {
      int rb = (w * 4 + j) * 8;
      int row = rb + rowi;
      int gs = g ^ (row & 7);
      gl_lds16((const char*)(A + (long)(m0 + row) * K + kt * 64) + gs * 16, ldsA + rb * 128);
      gl_lds16((const char*)(B + (long)(n0 + row) * K + kt * 64) + gs * 16, ldsB + rb * 128);
    }
    __syncthreads();
    #pragma unroll
    for (int ks = 0; ks < 2; ++ks) {
      bf16x8 af[4], bfr[4];
      #pragma unroll
      for (int i = 0; i < 4; ++i) {
        int rowA = wm * 64 + i * 16 + cl;
        int c = ks * 4 + rg;
        af[i] = *(const bf16x8*)(ldsA + rowA * 128 + ((c ^ (rowA & 7)) * 16));
        int rowB = wn * 64 + i * 16 + cl;
        bfr[i] = *(const bf16x8*)(ldsB + rowB * 128 + ((c ^ (rowB & 7)) * 16));
      }
      #pragma unroll
      for (int mf = 0; mf < 4; ++mf)
        #pragma unroll
        for (int nf = 0; nf < 4; ++nf)
          acc[mf][nf] = __builtin_amdgcn_mfma_f32_16x16x32_bf16(af[mf], bfr[nf], acc[mf][nf], 0, 0, 0);
    }
    __syncthreads();
  }

  #pragma unroll
  for (int mf = 0; mf < 4; ++mf) {
    #pragma unroll
    for (int nf = 0; nf < 4; ++nf) {
      int n = n0 + wn * 64 + nf * 16 + cl;
      float bval = bias[n];
      int mb = m0 + wm * 64 + mf * 16 + rg * 4;
      if (MODE == 0) {
        #pragma unroll
        for (int rr = 0; rr < 4; ++rr)
          outF[(long)(mb + rr) * ldF + n] = acc[mf][nf][rr] + bval;
      } else {
        if (n < 1024) {
          #pragma unroll
          for (int rr = 0; rr < 4; ++rr)
            outK[(long)(mb + rr) * 1024 + n] = (bf16)(acc[mf][nf][rr] + bval);
        } else {
          bf16x4 p;
          #pragma unroll
          for (int rr = 0; rr < 4; ++rr) p[rr] = (bf16)(acc[mf][nf][rr] + bval);
          *(bf16x4*)(outVT + (long)(n - 1024) * SKP + mb) = p;
        }
      }
    }
  }
}

// ---------------- rmsnorm + rope ----------------

__global__ __launch_bounds__(256) void k_fuse_q(const float* __restrict__ QP,
    bf16* __restrict__ Qr, const float* __restrict__ gg,
    const float* __restrict__ cosT, const float* __restrict__ sinT) {
  int row = blockIdx.x, tid = threadIdx.x;
  int d0 = tid * 4;
  float4 t = *(const float4*)(QP + (long)row * DIM + d0);
  float v0 = t.x, v1 = t.y, v2 = t.z, v3 = t.w;
  float ss = v0 * v0 + v1 * v1 + v2 * v2 + v3 * v3;
  #pragma unroll
  for (int m = 1; m < 64; m <<= 1) ss += __shfl_xor(ss, m);
  __shared__ float red[4];
  if ((tid & 63) == 0) red[tid >> 6] = ss;
  __syncthreads();
  float rn = rsqrtf((red[0] + red[1] + red[2] + red[3]) * (1.0f / DIM) + 1e-6f);
  v0 *= rn * gg[d0]; v1 *= rn * gg[d0 + 1]; v2 *= rn * gg[d0 + 2]; v3 *= rn * gg[d0 + 3];
  int i0 = (d0 & 127) >> 1;
  float c0 = cosT[(long)row * HALF + i0], s0 = sinT[(long)row * HALF + i0];
  float c1 = cosT[(long)row * HALF + i0 + 1], s1 = sinT[(long)row * HALF + i0 + 1];
  bf16x4 o = { (bf16)(v0 * c0 - v1 * s0), (bf16)(v0 * s0 + v1 * c0),
               (bf16)(v2 * c1 - v3 * s1), (bf16)(v2 * s1 + v3 * c1) };
  *(bf16x4*)(Qr + (long)row * DIM + d0) = o;
}

__global__ __launch_bounds__(256) void k_fuse_k(bf16* __restrict__ KP,
    const float* __restrict__ gg, const float* __restrict__ cosT,
    const float* __restrict__ sinT) {
  int row = blockIdx.x, tid = threadIdx.x;
  int d0 = tid * 4;
  bf16x4 t = *(const bf16x4*)(KP + (long)row * DIM + d0);
  float v0 = (float)t[0], v1 = (float)t[1], v2 = (float)t[2], v3 = (float)t[3];
  float ss = v0 * v0 + v1 * v1 + v2 * v2 + v3 * v3;
  #pragma unroll
  for (int m = 1; m < 64; m <<= 1) ss += __shfl_xor(ss, m);
  __shared__ float red[4];
  if ((tid & 63) == 0) red[tid >> 6] = ss;
  __syncthreads();
  float rn = rsqrtf((red[0] + red[1] + red[2] + red[3]) * (1.0f / DIM) + 1e-6f);
  v0 *= rn * gg[d0]; v1 *= rn * gg[d0 + 1]; v2 *= rn * gg[d0 + 2]; v3 *= rn * gg[d0 + 3];
  int i0 = (d0 & 127) >> 1;
  float c0 = cosT[(long)row * HALF + i0], s0 = sinT[(long)row * HALF + i0];
  float c1 = cosT[(long)row * HALF + i0 + 1], s1 = sinT[(long)row * HALF + i0 + 1];
  bf16x4 o = { (bf16)(v0 * c0 - v1 * s0), (bf16)(v0 * s0 + v1 * c0),
               (bf16)(v2 * c1 - v3 * s1), (bf16)(v2 * s1 + v3 * c1) };
  *(bf16x4*)(KP + (long)row * DIM + d0) = o;
}

// ---------------- flash attention: 4 waves x 32q = 128 q/block, KVBLK=64 ----------------
// Single-buffered K/V (TLP via 4 blocks/CU hides stage latency), per-wave 2KB P
// reused across both mf halves, defer-max rescale (THR=6).
// LDS: K 16K | V 16K | P 4x2K = 40KB -> 4 blocks/CU, 16 waves/CU.

__global__ __launch_bounds__(256, 4)
void k_attn(const bf16* __restrict__ Kr, const bf16* __restrict__ VT,
            const bf16* __restrict__ Qr, const float* __restrict__ biasA,
            float* __restrict__ Opart, float* __restrict__ ml) {
  __shared__ char lds[40960];
  char* ldsK = lds;            // [64 keys][256 B]
  char* ldsV = lds + 16384;    // [128 d][128 B]
  int tid = threadIdx.x, w = tid >> 6, lane = tid & 63;
  char* ldsP = lds + 32768 + w * 2048;  // per-wave [16 q][128 B], reused per mf
  int bid = blockIdx.x;
  int swz = (bid & 7) * 128 + (bid >> 3);  // XCD-chunked
  int sp = swz >> 5, h = (swz >> 2) & 7, qb = swz & 3;
  int t0 = sp * TPS;
  int t1 = t0 + TPS; if (t1 > NT) t1 = NT;
  int cl = lane & 15, rg = lane >> 4;
  int qbase = qb * 128 + w * 32;

  bf16x8 qf[2][4];
  #pragma unroll
  for (int mf = 0; mf < 2; ++mf)
    #pragma unroll
    for (int ks = 0; ks < 4; ++ks)
      qf[mf][ks] = *(const bf16x8*)(Qr + (long)(qbase + mf * 16 + cl) * DIM + h * HD + ks * 32 + rg * 8);

  f32x4 Oa[2][8] = {};
  float m_r[2][4], l_r[2][4];
  #pragma unroll
  for (int mf = 0; mf < 2; ++mf)
    #pragma unroll
    for (int r = 0; r < 4; ++r) { m_r[mf][r] = -1e30f; l_r[mf][r] = 0.f; }

  const float sc = 0.08838834764831845f;
  for (int t = t0; t < t1; ++t) {
    int k0 = t * 64;
    __syncthreads();   // all waves done reading previous tile's K/V
    {
      // K: wave w stages rows [w*16, w*16+16)
      int rK = lane >> 4, gK = lane & 15;
      #pragma unroll
      for (int j = 0; j < 4; ++j) {
        int rb = w * 16 + j * 4;
        int row = rb + rK;
        int gs = gK ^ (row & 7);
        gl_lds16((const char*)(Kr + (long)(k0 + row) * DIM + h * HD) + gs * 16,
                 ldsK + rb * 256);
      }
      // V: wave w stages d-rows [w*32, w*32+32)
      int rV = lane >> 3, gV = lane & 7;
      #pragma unroll
      for (int j = 0; j < 4; ++j) {
        int db = w * 32 + j * 8;
        int d = db + rV;
        int gs = gV ^ (d & 7);
        gl_lds16((const char*)(VT + (long)(h * HD + d) * SKP + k0) + gs * 16,
                 ldsV + db * 128);
      }
    }
    __syncthreads();   // staged data visible (vmcnt drained by barrier)

    f32x4 sa[2][4] = {};
    #pragma unroll
    for (int ks = 0; ks < 4; ++ks) {
      #pragma unroll
      for (int nf = 0; nf < 4; ++nf) {
        int key = nf * 16 + cl;
        int c = ks * 4 + rg;
        bf16x8 kb = *(const bf16x8*)(ldsK + key * 256 + ((c ^ (key & 7)) * 16));
        sa[0][nf] = __builtin_amdgcn_mfma_f32_16x16x32_bf16(qf[0][ks], kb, sa[0][nf], 0, 0, 0);
        sa[1][nf] = __builtin_amdgcn_mfma_f32_16x16x32_bf16(qf[1][ks], kb, sa[1][nf], 0, 0, 0);
      }
    }

    float bia[4];
    #pragma unroll
    for (int nf = 0; nf < 4; ++nf) bia[nf] = biasA[k0 + nf * 16 + cl];

    #pragma unroll
    for (int mf = 0; mf < 2; ++mf) {
      float sv[4][4];
      #pragma unroll
      for (int nf = 0; nf < 4; ++nf)
        #pragma unroll
        for (int r = 0; r < 4; ++r) sv[nf][r] = sa[mf][nf][r] * sc + bia[nf];
      float tm[4];
      #pragma unroll
      for (int r = 0; r < 4; ++r) {
        float v = fmaxf(fmaxf(sv[0][r], sv[1][r]), fmaxf(sv[2][r], sv[3][r]));
        v = fmaxf(v, __shfl_xor(v, 1));
        v = fmaxf(v, __shfl_xor(v, 2));
        v = fmaxf(v, __shfl_xor(v, 4));
        v = fmaxf(v, __shfl_xor(v, 8));
        tm[r] = v;
      }
      int grew = (tm[0] > m_r[mf][0] + 6.f) | (tm[1] > m_r[mf][1] + 6.f) |
                 (tm[2] > m_r[mf][2] + 6.f) | (tm[3] > m_r[mf][3] + 6.f);
      if (__any(grew)) {
        float scale[4];
        #pragma unroll
        for (int r = 0; r < 4; ++r) {
          float mn = fmaxf(m_r[mf][r], tm[r]);
          scale[r] = __expf(m_r[mf][r] - mn);
          m_r[mf][r] = mn;
          l_r[mf][r] *= scale[r];
        }
        #pragma unroll
        for (int df = 0; df < 8; ++df)
          #pragma unroll
          for (int r = 0; r < 4; ++r) Oa[mf][df][r] *= scale[r];
      }
      float rsum[4] = {0.f, 0.f, 0.f, 0.f};
      #pragma unroll
      for (int nf = 0; nf < 4; ++nf)
        #pragma unroll
        for (int r = 0; r < 4; ++r) {
          float p = __expf(sv[nf][r] - m_r[mf][r]);
          sv[nf][r] = p;
          rsum[r] += p;
        }
      #pragma unroll
      for (int r = 0; r < 4; ++r) {
        float rs = rsum[r];
        rs += __shfl_xor(rs, 1);
        rs += __shfl_xor(rs, 2);
        rs += __shfl_xor(rs, 4);
        rs += __shfl_xor(rs, 8);
        l_r[mf][r] += rs;
      }
      // P -> per-wave LDS (swizzled); same-wave read, no barrier needed
      #pragma unroll
      for (int nf = 0; nf < 4; ++nf)
        #pragma unroll
        for (int r = 0; r < 4; ++r) {
          int qr = rg * 4 + r;
          int col = nf * 16 + cl;
          int gp = (col >> 3) ^ (qr & 7);
          *(bf16*)(ldsP + qr * 128 + gp * 16 + (col & 7) * 2) = (bf16)sv[nf][r];
        }
      #pragma unroll
      for (int ks = 0; ks < 2; ++ks) {
        int c = ks * 4 + rg;
        bf16x8 pa = *(const bf16x8*)(ldsP + cl * 128 + ((c ^ (cl & 7)) * 16));
        #pragma unroll
        for (int df = 0; df < 8; ++df) {
          int d = df * 16 + cl;
          bf16x8 vb = *(const bf16x8*)(ldsV + d * 128 + ((c ^ (d & 7)) * 16));
          Oa[mf][df] = __builtin_amdgcn_mfma_f32_16x16x32_bf16(pa, vb, Oa[mf][df], 0, 0, 0);
        }
      }
    }
  }

  long rowb = (long)(sp * HEADS + h) * SQ + qbase;
  #pragma unroll
  for (int mf = 0; mf < 2; ++mf) {
    #pragma unroll
    for (int df = 0; df < 8; ++df)
      #pragma unroll
      for (int r = 0; r < 4; ++r) {
        int qr = mf * 16 + rg * 4 + r;
        Opart[(rowb + qr) * HD + df * 16 + cl] = Oa[mf][df][r];
      }
    if (cl == 0) {
      #pragma unroll
      for (int r = 0; r < 4; ++r) {
        int qr = mf * 16 + rg * 4 + r;
        ml[(rowb + qr) * 2] = m_r[mf][r];
        ml[(rowb + qr) * 2 + 1] = l_r[mf][r];
      }
    }
  }
}

__global__ __launch_bounds__(128) void k_combine(const float* __restrict__ Opart,
    const float* __restrict__ ml, bf16* __restrict__ AO) {
  int bid = blockIdx.x;
  int h = bid >> 9, qq = bid & 511;
  int d = threadIdx.x;
  float M = -1e30f;
  #pragma unroll 4
  for (int s2 = 0; s2 < NSPLIT; ++s2) {
    long mi = (long)(s2 * HEADS + h) * SQ + qq;
    M = fmaxf(M, ml[mi * 2]);
  }
  float L = 0.f, acc = 0.f;
  #pragma unroll 4
  for (int s2 = 0; s2 < NSPLIT; ++s2) {
    long mi = (long)(s2 * HEADS + h) * SQ + qq;
    float wgt = __expf(ml[mi * 2] - M);
    L += wgt * ml[mi * 2 + 1];
    acc += wgt * Opart[mi * HD + d];
  }
  AO[(long)qq * DIM + h * HD + d] = (bf16)(acc / L);
}

// ---------------- host ----------------

extern "C" void kernel_launch(void* const* d_in, const int* in_sizes, int n_in,
                              void* d_out, int out_size, void* d_ws, size_t ws_size,
                              hipStream_t stream) {
  const float* x     = (const float*)d_in[0];
  const float* mem   = (const float*)d_in[1];
  const int*   mask  = (const int*)d_in[2];
  const float* cos_q = (const float*)d_in[3];
  const float* sin_q = (const float*)d_in[4];
  const float* cos_k = (const float*)d_in[5];
  const float* sin_k = (const float*)d_in[6];
  const float* Wq    = (const float*)d_in[7];
  const float* bq    = (const float*)d_in[8];
  const float* Wk    = (const float*)d_in[9];
  const float* bk    = (const float*)d_in[10];
  const float* Wv    = (const float*)d_in[11];
  const float* bv    = (const float*)d_in[12];
  const float* Wo    = (const float*)d_in[13];
  const float* bo    = (const float*)d_in[14];
  const float* gq    = (const float*)d_in[15];
  const float* gk    = (const float*)d_in[16];

  char* ws = (char*)d_ws;
  bf16*  memb = (bf16*)(ws + OFF_MEMB);
  bf16*  xb   = (bf16*)(ws + OFF_XB);
  bf16*  WkvB = (bf16*)(ws + OFF_WKV);
  bf16*  WqB  = (bf16*)(ws + OFF_WQ);
  bf16*  WoB  = (bf16*)(ws + OFF_WO);
  float* bKV  = (float*)(ws + OFF_BKV);
  bf16*  Kpre = (bf16*)(ws + OFF_KPRE);
  bf16*  VT   = (bf16*)(ws + OFF_VT);
  float* Qpre = (float*)(ws + OFF_QPRE);
  bf16*  Qr   = (bf16*)(ws + OFF_QR);
  float* biasA= (float*)(ws + OFF_BIAS);
  float* Opart= (float*)(ws + OFF_OP);
  float* mlb  = (float*)(ws + OFF_ML);
  bf16*  AO   = (bf16*)(ws + OFF_AO);

  k_cvt_mem<<<dim3((SKP * DIM / 8 + 255) / 256), dim3(256), 0, stream>>>(mem, memb);
  k_cvt<<<dim3(SQ * DIM / 8 / 256), dim3(256), 0, stream>>>(x, xb, (long)(SQ * DIM / 8));
  k_cvt<<<dim3(DIM * DIM / 8 / 256), dim3(256), 0, stream>>>(Wq, WqB, (long)(DIM * DIM / 8));
  k_cvt<<<dim3(DIM * DIM / 8 / 256), dim3(256), 0, stream>>>(Wo, WoB, (long)(DIM * DIM / 8));
  k_build_wkv<<<dim3(2048 * DIM / 8 / 256), dim3(256), 0, stream>>>(Wk, Wv, bk, bv, WkvB, bKV);
  k_bias<<<dim3((SKP + 255) / 256), dim3(256), 0, stream>>>(mask, biasA);

  k_gemm<0><<<dim3(4 * 8), dim3(256), 0, stream>>>(xb, WqB, bq, 4, 8, Qpre, DIM,
                                                   (bf16*)nullptr, (bf16*)nullptr);
  k_gemm<1><<<dim3(245 * 16), dim3(256), 0, stream>>>(memb, WkvB, bKV, 245, 16,
                                                      (float*)nullptr, 0, Kpre, VT);

  k_fuse_q<<<dim3(SQ), dim3(256), 0, stream>>>(Qpre, Qr, gq, cos_q, sin_q);
  k_fuse_k<<<dim3(SK), dim3(256), 0, stream>>>(Kpre, gk, cos_k, sin_k);

  k_attn<<<dim3(NSPLIT * HEADS * 4), dim3(256), 0, stream>>>(Kpre, VT, Qr, biasA, Opart, mlb);
  k_combine<<<dim3(HEADS * SQ), dim3(128), 0, stream>>>(Opart, mlb, AO);

  k_gemm<0><<<dim3(4 * 8), dim3(256), 0, stream>>>(AO, WoB, bo, 4, 8, (float*)d_out, DIM,
                                                   (bf16*)nullptr, (bf16*)nullptr);
  (void)in_sizes; (void)n_in; (void)out_size; (void)ws_size;
}

// Round 4
// 406.767 us; speedup vs baseline: 2.0583x; 2.0583x over previous
//
#include <hip/hip_runtime.h>
#include <cstdint>

typedef __bf16 bf16;
typedef __bf16 bf16x8 __attribute__((ext_vector_type(8)));
typedef __bf16 bf16x4 __attribute__((ext_vector_type(4)));
typedef float f32x4 __attribute__((ext_vector_type(4)));

#define DEVINL __device__ __forceinline__

namespace {
constexpr int DIM = 1024, HEADS = 8, HD = 128, HALF = 64;
constexpr int SQ = 512;
constexpr int SK = 31290;
constexpr int SKP = 31360;               // 245*128
constexpr int NT = SKP / 64;             // 490 kv tiles
constexpr int NSPLIT = 32;
constexpr int TPS = (NT + NSPLIT - 1) / NSPLIT;  // 16

// workspace layout (bytes). Opart ALIASES [memb|xb|Wkv] which are dead by attn time.
constexpr long OFF_MEMB = 0;
constexpr long OFF_XB   = OFF_MEMB + (long)SKP * DIM * 2;
constexpr long OFF_WKV  = OFF_XB + (long)SQ * DIM * 2;
constexpr long OFF_WQ   = OFF_WKV + 2048L * DIM * 2;
constexpr long OFF_WO   = OFF_WQ + (long)DIM * DIM * 2;
constexpr long OFF_BKV  = OFF_WO + (long)DIM * DIM * 2;
constexpr long OFF_KPRE = OFF_BKV + 2048L * 4;
constexpr long OFF_VT   = OFF_KPRE + (long)SKP * DIM * 2;
constexpr long OFF_QPRE = OFF_VT + (long)DIM * SKP * 2;
constexpr long OFF_QR   = OFF_QPRE + (long)SQ * DIM * 4;
constexpr long OFF_BIAS = OFF_QR + (long)SQ * DIM * 2;
constexpr long OFF_ML   = OFF_BIAS + (long)SKP * 4;
constexpr long OFF_AO   = OFF_ML + (long)NSPLIT * HEADS * SQ * 2 * 4;
constexpr long OFF_OP   = OFF_MEMB;      // 67.1MB, < OFF_KPRE (73.7MB): only dead bufs
}

DEVINL void gl_lds16(const void* g, void* l) {
  __builtin_amdgcn_global_load_lds(
      (__attribute__((address_space(1))) void*)(void*)g,
      (__attribute__((address_space(3))) void*)l, 16, 0, 0);
}

// ---------------- converts ----------------

__global__ __launch_bounds__(256) void k_cvt_mem(const float* __restrict__ mem,
                                                 bf16* __restrict__ memb) {
  long i = (long)blockIdx.x * 256 + threadIdx.x;
  long e = i * 8;
  if (e >= (long)SKP * DIM) return;
  int row = (int)(e >> 10);
  bf16x8 o;
  if (row < SK) {
    float4 a = *(const float4*)(mem + e);
    float4 b = *(const float4*)(mem + e + 4);
    o[0] = (bf16)a.x; o[1] = (bf16)a.y; o[2] = (bf16)a.z; o[3] = (bf16)a.w;
    o[4] = (bf16)b.x; o[5] = (bf16)b.y; o[6] = (bf16)b.z; o[7] = (bf16)b.w;
  } else {
    #pragma unroll
    for (int j = 0; j < 8; ++j) o[j] = (bf16)0.0f;
  }
  *(bf16x8*)(memb + e) = o;
}

__global__ __launch_bounds__(256) void k_cvt(const float* __restrict__ s,
                                             bf16* __restrict__ d, long n8) {
  long i = (long)blockIdx.x * 256 + threadIdx.x;
  if (i >= n8) return;
  long e = i * 8;
  float4 a = *(const float4*)(s + e);
  float4 b = *(const float4*)(s + e + 4);
  bf16x8 o;
  o[0] = (bf16)a.x; o[1] = (bf16)a.y; o[2] = (bf16)a.z; o[3] = (bf16)a.w;
  o[4] = (bf16)b.x; o[5] = (bf16)b.y; o[6] = (bf16)b.z; o[7] = (bf16)b.w;
  *(bf16x8*)(d + e) = o;
}

__global__ __launch_bounds__(256) void k_build_wkv(const float* __restrict__ Wk,
    const float* __restrict__ Wv, const float* __restrict__ bk,
    const float* __restrict__ bv, bf16* __restrict__ WB, float* __restrict__ bKV) {
  long i = (long)blockIdx.x * 256 + threadIdx.x;
  long e = i * 8;
  if (e < 2048L * 1024) {
    int n = (int)(e >> 10);
    const float* src = (n < 1024) ? (Wk + e) : (Wv + e - 1024L * 1024);
    float4 a = *(const float4*)(src);
    float4 b = *(const float4*)(src + 4);
    bf16x8 o;
    o[0] = (bf16)a.x; o[1] = (bf16)a.y; o[2] = (bf16)a.z; o[3] = (bf16)a.w;
    o[4] = (bf16)b.x; o[5] = (bf16)b.y; o[6] = (bf16)b.z; o[7] = (bf16)b.w;
    *(bf16x8*)(WB + e) = o;
  }
  if (i < 2048) bKV[i] = (i < 1024) ? bk[i] : bv[i - 1024];
}

__global__ __launch_bounds__(256) void k_bias(const int* __restrict__ mask,
                                              float* __restrict__ biasA) {
  int k = blockIdx.x * 256 + threadIdx.x;
  if (k < SKP) biasA[k] = (k < SK && mask[k] != 0) ? 0.0f : -1e30f;
}

// ---------------- GEMM: C = A(MxK) * B(NxK)^T + bias ----------------
// 128x128 tile, BK=64, 256 threads. XCD-chunked block swizzle for A/B L2 reuse.

template<int MODE>
__global__ __launch_bounds__(256, 2)
void k_gemm(const bf16* __restrict__ A, const bf16* __restrict__ B,
            const float* __restrict__ bias, int Mtiles, int Ntiles,
            float* __restrict__ outF, int ldF,
            bf16* __restrict__ outK, bf16* __restrict__ outVT) {
  constexpr int K = 1024;
  __shared__ char lds[32768];
  char* ldsA = lds;
  char* ldsB = lds + 16384;
  int tid = threadIdx.x;
  int w = tid >> 6, lane = tid & 63;
  int cpx = gridDim.x >> 3;                       // grids are %8==0
  int bid = (blockIdx.x & 7) * cpx + (blockIdx.x >> 3);
  int mt = bid / Ntiles, nt = bid % Ntiles;
  int m0 = mt * 128, n0 = nt * 128;
  int wm = w >> 1, wn = w & 1;
  int cl = lane & 15, rg = lane >> 4;

  f32x4 acc[4][4] = {};

  int rowi = lane >> 3, g = lane & 7;
  for (int kt = 0; kt < K / 64; ++kt) {
    #pragma unroll
    for (int j = 0; j < 4; ++j) {
      int rb = (w * 4 + j) * 8;
      int row = rb + rowi;
      int gs = g ^ (row & 7);
      gl_lds16((const char*)(A + (long)(m0 + row) * K + kt * 64) + gs * 16, ldsA + rb * 128);
      gl_lds16((const char*)(B + (long)(n0 + row) * K + kt * 64) + gs * 16, ldsB + rb * 128);
    }
    __syncthreads();
    #pragma unroll
    for (int ks = 0; ks < 2; ++ks) {
      bf16x8 af[4], bfr[4];
      #pragma unroll
      for (int i = 0; i < 4; ++i) {
        int rowA = wm * 64 + i * 16 + cl;
        int c = ks * 4 + rg;
        af[i] = *(const bf16x8*)(ldsA + rowA * 128 + ((c ^ (rowA & 7)) * 16));
        int rowB = wn * 64 + i * 16 + cl;
        bfr[i] = *(const bf16x8*)(ldsB + rowB * 128 + ((c ^ (rowB & 7)) * 16));
      }
      #pragma unroll
      for (int mf = 0; mf < 4; ++mf)
        #pragma unroll
        for (int nf = 0; nf < 4; ++nf)
          acc[mf][nf] = __builtin_amdgcn_mfma_f32_16x16x32_bf16(af[mf], bfr[nf], acc[mf][nf], 0, 0, 0);
    }
    __syncthreads();
  }

  #pragma unroll
  for (int mf = 0; mf < 4; ++mf) {
    #pragma unroll
    for (int nf = 0; nf < 4; ++nf) {
      int n = n0 + wn * 64 + nf * 16 + cl;
      float bval = bias[n];
      int mb = m0 + wm * 64 + mf * 16 + rg * 4;
      if (MODE == 0) {
        #pragma unroll
        for (int rr = 0; rr < 4; ++rr)
          outF[(long)(mb + rr) * ldF + n] = acc[mf][nf][rr] + bval;
      } else {
        if (n < 1024) {
          #pragma unroll
          for (int rr = 0; rr < 4; ++rr)
            outK[(long)(mb + rr) * 1024 + n] = (bf16)(acc[mf][nf][rr] + bval);
        } else {
          bf16x4 p;
          #pragma unroll
          for (int rr = 0; rr < 4; ++rr) p[rr] = (bf16)(acc[mf][nf][rr] + bval);
          *(bf16x4*)(outVT + (long)(n - 1024) * SKP + mb) = p;
        }
      }
    }
  }
}

// ---------------- rmsnorm + rope ----------------

__global__ __launch_bounds__(256) void k_fuse_q(const float* __restrict__ QP,
    bf16* __restrict__ Qr, const float* __restrict__ gg,
    const float* __restrict__ cosT, const float* __restrict__ sinT) {
  int row = blockIdx.x, tid = threadIdx.x;
  int d0 = tid * 4;
  float4 t = *(const float4*)(QP + (long)row * DIM + d0);
  float v0 = t.x, v1 = t.y, v2 = t.z, v3 = t.w;
  float ss = v0 * v0 + v1 * v1 + v2 * v2 + v3 * v3;
  #pragma unroll
  for (int m = 1; m < 64; m <<= 1) ss += __shfl_xor(ss, m);
  __shared__ float red[4];
  if ((tid & 63) == 0) red[tid >> 6] = ss;
  __syncthreads();
  float rn = rsqrtf((red[0] + red[1] + red[2] + red[3]) * (1.0f / DIM) + 1e-6f);
  v0 *= rn * gg[d0]; v1 *= rn * gg[d0 + 1]; v2 *= rn * gg[d0 + 2]; v3 *= rn * gg[d0 + 3];
  int i0 = (d0 & 127) >> 1;
  float c0 = cosT[(long)row * HALF + i0], s0 = sinT[(long)row * HALF + i0];
  float c1 = cosT[(long)row * HALF + i0 + 1], s1 = sinT[(long)row * HALF + i0 + 1];
  bf16x4 o = { (bf16)(v0 * c0 - v1 * s0), (bf16)(v0 * s0 + v1 * c0),
               (bf16)(v2 * c1 - v3 * s1), (bf16)(v2 * s1 + v3 * c1) };
  *(bf16x4*)(Qr + (long)row * DIM + d0) = o;
}

__global__ __launch_bounds__(256) void k_fuse_k(bf16* __restrict__ KP,
    const float* __restrict__ gg, const float* __restrict__ cosT,
    const float* __restrict__ sinT) {
  int row = blockIdx.x, tid = threadIdx.x;
  int d0 = tid * 4;
  bf16x4 t = *(const bf16x4*)(KP + (long)row * DIM + d0);
  float v0 = (float)t[0], v1 = (float)t[1], v2 = (float)t[2], v3 = (float)t[3];
  float ss = v0 * v0 + v1 * v1 + v2 * v2 + v3 * v3;
  #pragma unroll
  for (int m = 1; m < 64; m <<= 1) ss += __shfl_xor(ss, m);
  __shared__ float red[4];
  if ((tid & 63) == 0) red[tid >> 6] = ss;
  __syncthreads();
  float rn = rsqrtf((red[0] + red[1] + red[2] + red[3]) * (1.0f / DIM) + 1e-6f);
  v0 *= rn * gg[d0]; v1 *= rn * gg[d0 + 1]; v2 *= rn * gg[d0 + 2]; v3 *= rn * gg[d0 + 3];
  int i0 = (d0 & 127) >> 1;
  float c0 = cosT[(long)row * HALF + i0], s0 = sinT[(long)row * HALF + i0];
  float c1 = cosT[(long)row * HALF + i0 + 1], s1 = sinT[(long)row * HALF + i0 + 1];
  bf16x4 o = { (bf16)(v0 * c0 - v1 * s0), (bf16)(v0 * s0 + v1 * c0),
               (bf16)(v2 * c1 - v3 * s1), (bf16)(v2 * s1 + v3 * c1) };
  *(bf16x4*)(KP + (long)row * DIM + d0) = o;
}

// ---------------- flash attention: 4 waves x 32q = 128 q/block, KVBLK=64 ----------------
// Single-buffered K/V (TLP via multiple blocks/CU hides stage latency), per-wave 2KB P,
// defer-max rescale (THR=6). LDS 40KB. launch_bounds(256,2): 256-VGPR budget —
// (256,4) caused a 64-VGPR spill catastrophe (963MB scratch writes, round 3).

__global__ __launch_bounds__(256, 2)
void k_attn(const bf16* __restrict__ Kr, const bf16* __restrict__ VT,
            const bf16* __restrict__ Qr, const float* __restrict__ biasA,
            float* __restrict__ Opart, float* __restrict__ ml) {
  __shared__ char lds[40960];
  char* ldsK = lds;            // [64 keys][256 B]
  char* ldsV = lds + 16384;    // [128 d][128 B]
  int tid = threadIdx.x, w = tid >> 6, lane = tid & 63;
  char* ldsP = lds + 32768 + w * 2048;  // per-wave [16 q][128 B], reused per mf
  int bid = blockIdx.x;
  int swz = (bid & 7) * 128 + (bid >> 3);  // XCD-chunked
  int sp = swz >> 5, h = (swz >> 2) & 7, qb = swz & 3;
  int t0 = sp * TPS;
  int t1 = t0 + TPS; if (t1 > NT) t1 = NT;
  int cl = lane & 15, rg = lane >> 4;
  int qbase = qb * 128 + w * 32;

  bf16x8 qf[2][4];
  #pragma unroll
  for (int mf = 0; mf < 2; ++mf)
    #pragma unroll
    for (int ks = 0; ks < 4; ++ks)
      qf[mf][ks] = *(const bf16x8*)(Qr + (long)(qbase + mf * 16 + cl) * DIM + h * HD + ks * 32 + rg * 8);

  f32x4 Oa[2][8] = {};
  float m_r[2][4], l_r[2][4];
  #pragma unroll
  for (int mf = 0; mf < 2; ++mf)
    #pragma unroll
    for (int r = 0; r < 4; ++r) { m_r[mf][r] = -1e30f; l_r[mf][r] = 0.f; }

  const float sc = 0.08838834764831845f;
  for (int t = t0; t < t1; ++t) {
    int k0 = t * 64;
    __syncthreads();   // all waves done reading previous tile's K/V
    {
      // K: wave w stages rows [w*16, w*16+16)
      int rK = lane >> 4, gK = lane & 15;
      #pragma unroll
      for (int j = 0; j < 4; ++j) {
        int rb = w * 16 + j * 4;
        int row = rb + rK;
        int gs = gK ^ (row & 7);
        gl_lds16((const char*)(Kr + (long)(k0 + row) * DIM + h * HD) + gs * 16,
                 ldsK + rb * 256);
      }
      // V: wave w stages d-rows [w*32, w*32+32)
      int rV = lane >> 3, gV = lane & 7;
      #pragma unroll
      for (int j = 0; j < 4; ++j) {
        int db = w * 32 + j * 8;
        int d = db + rV;
        int gs = gV ^ (d & 7);
        gl_lds16((const char*)(VT + (long)(h * HD + d) * SKP + k0) + gs * 16,
                 ldsV + db * 128);
      }
    }
    __syncthreads();   // staged data visible (vmcnt drained by barrier)

    f32x4 sa[2][4] = {};
    #pragma unroll
    for (int ks = 0; ks < 4; ++ks) {
      #pragma unroll
      for (int nf = 0; nf < 4; ++nf) {
        int key = nf * 16 + cl;
        int c = ks * 4 + rg;
        bf16x8 kb = *(const bf16x8*)(ldsK + key * 256 + ((c ^ (key & 7)) * 16));
        sa[0][nf] = __builtin_amdgcn_mfma_f32_16x16x32_bf16(qf[0][ks], kb, sa[0][nf], 0, 0, 0);
        sa[1][nf] = __builtin_amdgcn_mfma_f32_16x16x32_bf16(qf[1][ks], kb, sa[1][nf], 0, 0, 0);
      }
    }

    float bia[4];
    #pragma unroll
    for (int nf = 0; nf < 4; ++nf) bia[nf] = biasA[k0 + nf * 16 + cl];

    #pragma unroll
    for (int mf = 0; mf < 2; ++mf) {
      // softmax in place on sa[mf] (saves a separate sv[4][4] -> ~16 VGPRs)
      #pragma unroll
      for (int nf = 0; nf < 4; ++nf)
        #pragma unroll
        for (int r = 0; r < 4; ++r) sa[mf][nf][r] = sa[mf][nf][r] * sc + bia[nf];
      float tm[4];
      #pragma unroll
      for (int r = 0; r < 4; ++r) {
        float v = fmaxf(fmaxf(sa[mf][0][r], sa[mf][1][r]), fmaxf(sa[mf][2][r], sa[mf][3][r]));
        v = fmaxf(v, __shfl_xor(v, 1));
        v = fmaxf(v, __shfl_xor(v, 2));
        v = fmaxf(v, __shfl_xor(v, 4));
        v = fmaxf(v, __shfl_xor(v, 8));
        tm[r] = v;
      }
      int grew = (tm[0] > m_r[mf][0] + 6.f) | (tm[1] > m_r[mf][1] + 6.f) |
                 (tm[2] > m_r[mf][2] + 6.f) | (tm[3] > m_r[mf][3] + 6.f);
      if (__any(grew)) {
        float scale[4];
        #pragma unroll
        for (int r = 0; r < 4; ++r) {
          float mn = fmaxf(m_r[mf][r], tm[r]);
          scale[r] = __expf(m_r[mf][r] - mn);
          m_r[mf][r] = mn;
          l_r[mf][r] *= scale[r];
        }
        #pragma unroll
        for (int df = 0; df < 8; ++df)
          #pragma unroll
          for (int r = 0; r < 4; ++r) Oa[mf][df][r] *= scale[r];
      }
      float rsum[4] = {0.f, 0.f, 0.f, 0.f};
      #pragma unroll
      for (int nf = 0; nf < 4; ++nf)
        #pragma unroll
        for (int r = 0; r < 4; ++r) {
          float p = __expf(sa[mf][nf][r] - m_r[mf][r]);
          sa[mf][nf][r] = p;
          rsum[r] += p;
        }
      #pragma unroll
      for (int r = 0; r < 4; ++r) {
        float rs = rsum[r];
        rs += __shfl_xor(rs, 1);
        rs += __shfl_xor(rs, 2);
        rs += __shfl_xor(rs, 4);
        rs += __shfl_xor(rs, 8);
        l_r[mf][r] += rs;
      }
      // P -> per-wave LDS (swizzled); same-wave read, no barrier needed
      #pragma unroll
      for (int nf = 0; nf < 4; ++nf)
        #pragma unroll
        for (int r = 0; r < 4; ++r) {
          int qr = rg * 4 + r;
          int col = nf * 16 + cl;
          int gp = (col >> 3) ^ (qr & 7);
          *(bf16*)(ldsP + qr * 128 + gp * 16 + (col & 7) * 2) = (bf16)sa[mf][nf][r];
        }
      #pragma unroll
      for (int ks = 0; ks < 2; ++ks) {
        int c = ks * 4 + rg;
        bf16x8 pa = *(const bf16x8*)(ldsP + cl * 128 + ((c ^ (cl & 7)) * 16));
        #pragma unroll
        for (int df = 0; df < 8; ++df) {
          int d = df * 16 + cl;
          bf16x8 vb = *(const bf16x8*)(ldsV + d * 128 + ((c ^ (d & 7)) * 16));
          Oa[mf][df] = __builtin_amdgcn_mfma_f32_16x16x32_bf16(pa, vb, Oa[mf][df], 0, 0, 0);
        }
      }
    }
  }

  long rowb = (long)(sp * HEADS + h) * SQ + qbase;
  #pragma unroll
  for (int mf = 0; mf < 2; ++mf) {
    #pragma unroll
    for (int df = 0; df < 8; ++df)
      #pragma unroll
      for (int r = 0; r < 4; ++r) {
        int qr = mf * 16 + rg * 4 + r;
        Opart[(rowb + qr) * HD + df * 16 + cl] = Oa[mf][df][r];
      }
    if (cl == 0) {
      #pragma unroll
      for (int r = 0; r < 4; ++r) {
        int qr = mf * 16 + rg * 4 + r;
        ml[(rowb + qr) * 2] = m_r[mf][r];
        ml[(rowb + qr) * 2 + 1] = l_r[mf][r];
      }
    }
  }
}

__global__ __launch_bounds__(128) void k_combine(const float* __restrict__ Opart,
    const float* __restrict__ ml, bf16* __restrict__ AO) {
  int bid = blockIdx.x;
  int h = bid >> 9, qq = bid & 511;
  int d = threadIdx.x;
  float M = -1e30f;
  #pragma unroll 4
  for (int s2 = 0; s2 < NSPLIT; ++s2) {
    long mi = (long)(s2 * HEADS + h) * SQ + qq;
    M = fmaxf(M, ml[mi * 2]);
  }
  float L = 0.f, acc = 0.f;
  #pragma unroll 4
  for (int s2 = 0; s2 < NSPLIT; ++s2) {
    long mi = (long)(s2 * HEADS + h) * SQ + qq;
    float wgt = __expf(ml[mi * 2] - M);
    L += wgt * ml[mi * 2 + 1];
    acc += wgt * Opart[mi * HD + d];
  }
  AO[(long)qq * DIM + h * HD + d] = (bf16)(acc / L);
}

// ---------------- host ----------------

extern "C" void kernel_launch(void* const* d_in, const int* in_sizes, int n_in,
                              void* d_out, int out_size, void* d_ws, size_t ws_size,
                              hipStream_t stream) {
  const float* x     = (const float*)d_in[0];
  const float* mem   = (const float*)d_in[1];
  const int*   mask  = (const int*)d_in[2];
  const float* cos_q = (const float*)d_in[3];
  const float* sin_q = (const float*)d_in[4];
  const float* cos_k = (const float*)d_in[5];
  const float* sin_k = (const float*)d_in[6];
  const float* Wq    = (const float*)d_in[7];
  const float* bq    = (const float*)d_in[8];
  const float* Wk    = (const float*)d_in[9];
  const float* bk    = (const float*)d_in[10];
  const float* Wv    = (const float*)d_in[11];
  const float* bv    = (const float*)d_in[12];
  const float* Wo    = (const float*)d_in[13];
  const float* bo    = (const float*)d_in[14];
  const float* gq    = (const float*)d_in[15];
  const float* gk    = (const float*)d_in[16];

  char* ws = (char*)d_ws;
  bf16*  memb = (bf16*)(ws + OFF_MEMB);
  bf16*  xb   = (bf16*)(ws + OFF_XB);
  bf16*  WkvB = (bf16*)(ws + OFF_WKV);
  bf16*  WqB  = (bf16*)(ws + OFF_WQ);
  bf16*  WoB  = (bf16*)(ws + OFF_WO);
  float* bKV  = (float*)(ws + OFF_BKV);
  bf16*  Kpre = (bf16*)(ws + OFF_KPRE);
  bf16*  VT   = (bf16*)(ws + OFF_VT);
  float* Qpre = (float*)(ws + OFF_QPRE);
  bf16*  Qr   = (bf16*)(ws + OFF_QR);
  float* biasA= (float*)(ws + OFF_BIAS);
  float* Opart= (float*)(ws + OFF_OP);
  float* mlb  = (float*)(ws + OFF_ML);
  bf16*  AO   = (bf16*)(ws + OFF_AO);

  k_cvt_mem<<<dim3((SKP * DIM / 8 + 255) / 256), dim3(256), 0, stream>>>(mem, memb);
  k_cvt<<<dim3(SQ * DIM / 8 / 256), dim3(256), 0, stream>>>(x, xb, (long)(SQ * DIM / 8));
  k_cvt<<<dim3(DIM * DIM / 8 / 256), dim3(256), 0, stream>>>(Wq, WqB, (long)(DIM * DIM / 8));
  k_cvt<<<dim3(DIM * DIM / 8 / 256), dim3(256), 0, stream>>>(Wo, WoB, (long)(DIM * DIM / 8));
  k_build_wkv<<<dim3(2048 * DIM / 8 / 256), dim3(256), 0, stream>>>(Wk, Wv, bk, bv, WkvB, bKV);
  k_bias<<<dim3((SKP + 255) / 256), dim3(256), 0, stream>>>(mask, biasA);

  k_gemm<0><<<dim3(4 * 8), dim3(256), 0, stream>>>(xb, WqB, bq, 4, 8, Qpre, DIM,
                                                   (bf16*)nullptr, (bf16*)nullptr);
  k_gemm<1><<<dim3(245 * 16), dim3(256), 0, stream>>>(memb, WkvB, bKV, 245, 16,
                                                      (float*)nullptr, 0, Kpre, VT);

  k_fuse_q<<<dim3(SQ), dim3(256), 0, stream>>>(Qpre, Qr, gq, cos_q, sin_q);
  k_fuse_k<<<dim3(SK), dim3(256), 0, stream>>>(Kpre, gk, cos_k, sin_k);

  k_attn<<<dim3(NSPLIT * HEADS * 4), dim3(256), 0, stream>>>(Kpre, VT, Qr, biasA, Opart, mlb);
  k_combine<<<dim3(HEADS * SQ), dim3(128), 0, stream>>>(Opart, mlb, AO);

  k_gemm<0><<<dim3(4 * 8), dim3(256), 0, stream>>>(AO, WoB, bo, 4, 8, (float*)d_out, DIM,
                                                   (bf16*)nullptr, (bf16*)nullptr);
  (void)in_sizes; (void)n_in; (void)out_size; (void)ws_size;
}

// Round 5
// 380.351 us; speedup vs baseline: 2.2012x; 1.0695x over previous
//
#include <hip/hip_runtime.h>
#include <cstdint>

typedef __bf16 bf16;
typedef __bf16 bf16x8 __attribute__((ext_vector_type(8)));
typedef __bf16 bf16x4 __attribute__((ext_vector_type(4)));
typedef float f32x4 __attribute__((ext_vector_type(4)));

#define DEVINL __device__ __forceinline__

namespace {
constexpr int DIM = 1024, HEADS = 8, HD = 128, HALF = 64;
constexpr int SQ = 512;
constexpr int SK = 31290;
constexpr int SKP = 31360;               // 245*128
constexpr int NT = SKP / 64;             // 490 kv tiles
constexpr int NSPLIT = 24;               // balanced splits; EVERY split has >=20 tiles

// workspace layout (bytes). Opart ALIASES [memb|xb|Wkv] which are dead by attn time.
constexpr long OFF_MEMB = 0;
constexpr long OFF_XB   = OFF_MEMB + (long)SKP * DIM * 2;
constexpr long OFF_WKV  = OFF_XB + (long)SQ * DIM * 2;
constexpr long OFF_WQ   = OFF_WKV + 2048L * DIM * 2;
constexpr long OFF_WO   = OFF_WQ + (long)DIM * DIM * 2;
constexpr long OFF_BKV  = OFF_WO + (long)DIM * DIM * 2;
constexpr long OFF_KPRE = OFF_BKV + 2048L * 4;
constexpr long OFF_VT   = OFF_KPRE + (long)SKP * DIM * 2;
constexpr long OFF_QPRE = OFF_VT + (long)DIM * SKP * 2;
constexpr long OFF_QR   = OFF_QPRE + (long)SQ * DIM * 4;
constexpr long OFF_BIAS = OFF_QR + (long)SQ * DIM * 2;
constexpr long OFF_ML   = OFF_BIAS + (long)SKP * 4;
constexpr long OFF_AO   = OFF_ML + (long)NSPLIT * HEADS * SQ * 2 * 4;
constexpr long OFF_OP   = OFF_MEMB;      // 50.3MB, < OFF_KPRE (73.7MB): only dead bufs
}

DEVINL void gl_lds16(const void* g, void* l) {
  __builtin_amdgcn_global_load_lds(
      (__attribute__((address_space(1))) void*)(void*)g,
      (__attribute__((address_space(3))) void*)l, 16, 0, 0);
}

// ---------------- converts ----------------

__global__ __launch_bounds__(256) void k_cvt_mem(const float* __restrict__ mem,
                                                 bf16* __restrict__ memb) {
  long i = (long)blockIdx.x * 256 + threadIdx.x;
  long e = i * 8;
  if (e >= (long)SKP * DIM) return;
  int row = (int)(e >> 10);
  bf16x8 o;
  if (row < SK) {
    float4 a = *(const float4*)(mem + e);
    float4 b = *(const float4*)(mem + e + 4);
    o[0] = (bf16)a.x; o[1] = (bf16)a.y; o[2] = (bf16)a.z; o[3] = (bf16)a.w;
    o[4] = (bf16)b.x; o[5] = (bf16)b.y; o[6] = (bf16)b.z; o[7] = (bf16)b.w;
  } else {
    #pragma unroll
    for (int j = 0; j < 8; ++j) o[j] = (bf16)0.0f;
  }
  *(bf16x8*)(memb + e) = o;
}

__global__ __launch_bounds__(256) void k_cvt(const float* __restrict__ s,
                                             bf16* __restrict__ d, long n8) {
  long i = (long)blockIdx.x * 256 + threadIdx.x;
  if (i >= n8) return;
  long e = i * 8;
  float4 a = *(const float4*)(s + e);
  float4 b = *(const float4*)(s + e + 4);
  bf16x8 o;
  o[0] = (bf16)a.x; o[1] = (bf16)a.y; o[2] = (bf16)a.z; o[3] = (bf16)a.w;
  o[4] = (bf16)b.x; o[5] = (bf16)b.y; o[6] = (bf16)b.z; o[7] = (bf16)b.w;
  *(bf16x8*)(d + e) = o;
}

__global__ __launch_bounds__(256) void k_build_wkv(const float* __restrict__ Wk,
    const float* __restrict__ Wv, const float* __restrict__ bk,
    const float* __restrict__ bv, bf16* __restrict__ WB, float* __restrict__ bKV) {
  long i = (long)blockIdx.x * 256 + threadIdx.x;
  long e = i * 8;
  if (e < 2048L * 1024) {
    int n = (int)(e >> 10);
    const float* src = (n < 1024) ? (Wk + e) : (Wv + e - 1024L * 1024);
    float4 a = *(const float4*)(src);
    float4 b = *(const float4*)(src + 4);
    bf16x8 o;
    o[0] = (bf16)a.x; o[1] = (bf16)a.y; o[2] = (bf16)a.z; o[3] = (bf16)a.w;
    o[4] = (bf16)b.x; o[5] = (bf16)b.y; o[6] = (bf16)b.z; o[7] = (bf16)b.w;
    *(bf16x8*)(WB + e) = o;
  }
  if (i < 2048) bKV[i] = (i < 1024) ? bk[i] : bv[i - 1024];
}

__global__ __launch_bounds__(256) void k_bias(const int* __restrict__ mask,
                                              float* __restrict__ biasA) {
  int k = blockIdx.x * 256 + threadIdx.x;
  if (k < SKP) biasA[k] = (k < SK && mask[k] != 0) ? 0.0f : -1e30f;
}

// ---------------- GEMM: C = A(MxK) * B(NxK)^T + bias ----------------
// 128x128 tile, BK=64, 256 threads. XCD-chunked block swizzle for A/B L2 reuse.

template<int MODE>
__global__ __launch_bounds__(256, 2)
void k_gemm(const bf16* __restrict__ A, const bf16* __restrict__ B,
            const float* __restrict__ bias, int Mtiles, int Ntiles,
            float* __restrict__ outF, int ldF,
            bf16* __restrict__ outK, bf16* __restrict__ outVT) {
  constexpr int K = 1024;
  __shared__ char lds[32768];
  char* ldsA = lds;
  char* ldsB = lds + 16384;
  int tid = threadIdx.x;
  int w = tid >> 6, lane = tid & 63;
  int cpx = gridDim.x >> 3;                       // grids are %8==0
  int bid = (blockIdx.x & 7) * cpx + (blockIdx.x >> 3);
  int mt = bid / Ntiles, nt = bid % Ntiles;
  int m0 = mt * 128, n0 = nt * 128;
  int wm = w >> 1, wn = w & 1;
  int cl = lane & 15, rg = lane >> 4;

  f32x4 acc[4][4] = {};

  int rowi = lane >> 3, g = lane & 7;
  for (int kt = 0; kt < K / 64; ++kt) {
    #pragma unroll
    for (int j = 0; j < 4; ++j) {
      int rb = (w * 4 + j) * 8;
      int row = rb + rowi;
      int gs = g ^ (row & 7);
      gl_lds16((const char*)(A + (long)(m0 + row) * K + kt * 64) + gs * 16, ldsA + rb * 128);
      gl_lds16((const char*)(B + (long)(n0 + row) * K + kt * 64) + gs * 16, ldsB + rb * 128);
    }
    __syncthreads();
    #pragma unroll
    for (int ks = 0; ks < 2; ++ks) {
      bf16x8 af[4], bfr[4];
      #pragma unroll
      for (int i = 0; i < 4; ++i) {
        int rowA = wm * 64 + i * 16 + cl;
        int c = ks * 4 + rg;
        af[i] = *(const bf16x8*)(ldsA + rowA * 128 + ((c ^ (rowA & 7)) * 16));
        int rowB = wn * 64 + i * 16 + cl;
        bfr[i] = *(const bf16x8*)(ldsB + rowB * 128 + ((c ^ (rowB & 7)) * 16));
      }
      #pragma unroll
      for (int mf = 0; mf < 4; ++mf)
        #pragma unroll
        for (int nf = 0; nf < 4; ++nf)
          acc[mf][nf] = __builtin_amdgcn_mfma_f32_16x16x32_bf16(af[mf], bfr[nf], acc[mf][nf], 0, 0, 0);
    }
    __syncthreads();
  }

  #pragma unroll
  for (int mf = 0; mf < 4; ++mf) {
    #pragma unroll
    for (int nf = 0; nf < 4; ++nf) {
      int n = n0 + wn * 64 + nf * 16 + cl;
      float bval = bias[n];
      int mb = m0 + wm * 64 + mf * 16 + rg * 4;
      if (MODE == 0) {
        #pragma unroll
        for (int rr = 0; rr < 4; ++rr)
          outF[(long)(mb + rr) * ldF + n] = acc[mf][nf][rr] + bval;
      } else {
        if (n < 1024) {
          #pragma unroll
          for (int rr = 0; rr < 4; ++rr)
            outK[(long)(mb + rr) * 1024 + n] = (bf16)(acc[mf][nf][rr] + bval);
        } else {
          bf16x4 p;
          #pragma unroll
          for (int rr = 0; rr < 4; ++rr) p[rr] = (bf16)(acc[mf][nf][rr] + bval);
          *(bf16x4*)(outVT + (long)(n - 1024) * SKP + mb) = p;
        }
      }
    }
  }
}

// ---------------- rmsnorm + rope ----------------

__global__ __launch_bounds__(256) void k_fuse_q(const float* __restrict__ QP,
    bf16* __restrict__ Qr, const float* __restrict__ gg,
    const float* __restrict__ cosT, const float* __restrict__ sinT) {
  int row = blockIdx.x, tid = threadIdx.x;
  int d0 = tid * 4;
  float4 t = *(const float4*)(QP + (long)row * DIM + d0);
  float v0 = t.x, v1 = t.y, v2 = t.z, v3 = t.w;
  float ss = v0 * v0 + v1 * v1 + v2 * v2 + v3 * v3;
  #pragma unroll
  for (int m = 1; m < 64; m <<= 1) ss += __shfl_xor(ss, m);
  __shared__ float red[4];
  if ((tid & 63) == 0) red[tid >> 6] = ss;
  __syncthreads();
  float rn = rsqrtf((red[0] + red[1] + red[2] + red[3]) * (1.0f / DIM) + 1e-6f);
  v0 *= rn * gg[d0]; v1 *= rn * gg[d0 + 1]; v2 *= rn * gg[d0 + 2]; v3 *= rn * gg[d0 + 3];
  int i0 = (d0 & 127) >> 1;
  float c0 = cosT[(long)row * HALF + i0], s0 = sinT[(long)row * HALF + i0];
  float c1 = cosT[(long)row * HALF + i0 + 1], s1 = sinT[(long)row * HALF + i0 + 1];
  bf16x4 o = { (bf16)(v0 * c0 - v1 * s0), (bf16)(v0 * s0 + v1 * c0),
               (bf16)(v2 * c1 - v3 * s1), (bf16)(v2 * s1 + v3 * c1) };
  *(bf16x4*)(Qr + (long)row * DIM + d0) = o;
}

__global__ __launch_bounds__(256) void k_fuse_k(bf16* __restrict__ KP,
    const float* __restrict__ gg, const float* __restrict__ cosT,
    const float* __restrict__ sinT) {
  int row = blockIdx.x, tid = threadIdx.x;
  int d0 = tid * 4;
  bf16x4 t = *(const bf16x4*)(KP + (long)row * DIM + d0);
  float v0 = (float)t[0], v1 = (float)t[1], v2 = (float)t[2], v3 = (float)t[3];
  float ss = v0 * v0 + v1 * v1 + v2 * v2 + v3 * v3;
  #pragma unroll
  for (int m = 1; m < 64; m <<= 1) ss += __shfl_xor(ss, m);
  __shared__ float red[4];
  if ((tid & 63) == 0) red[tid >> 6] = ss;
  __syncthreads();
  float rn = rsqrtf((red[0] + red[1] + red[2] + red[3]) * (1.0f / DIM) + 1e-6f);
  v0 *= rn * gg[d0]; v1 *= rn * gg[d0 + 1]; v2 *= rn * gg[d0 + 2]; v3 *= rn * gg[d0 + 3];
  int i0 = (d0 & 127) >> 1;
  float c0 = cosT[(long)row * HALF + i0], s0 = sinT[(long)row * HALF + i0];
  float c1 = cosT[(long)row * HALF + i0 + 1], s1 = sinT[(long)row * HALF + i0 + 1];
  bf16x4 o = { (bf16)(v0 * c0 - v1 * s0), (bf16)(v0 * s0 + v1 * c0),
               (bf16)(v2 * c1 - v3 * s1), (bf16)(v2 * s1 + v3 * c1) };
  *(bf16x4*)(KP + (long)row * DIM + d0) = o;
}

// ---------------- flash attention: 4 waves x 32q, KVBLK=64 ----------------
// DS-pipe-issue-bound (rounds 2/4 identical 157us at same LDS op count).
// Cuts: l-sum via MFMA(P, ones) [-32 bperm/tile], group-max softmax
// [-24 bperm/tile], vb hoisted across mf [-16 b128/tile].
// LDS: K 16K | V 16K | P 4x4K = 48KB -> 3 blocks/CU.

__global__ __launch_bounds__(256, 2)
void k_attn(const bf16* __restrict__ Kr, const bf16* __restrict__ VT,
            const bf16* __restrict__ Qr, const float* __restrict__ biasA,
            float* __restrict__ Opart, float* __restrict__ ml) {
  __shared__ char lds[49152];
  char* ldsK = lds;            // [64 keys][256 B]
  char* ldsV = lds + 16384;    // [128 d][128 B]
  int tid = threadIdx.x, w = tid >> 6, lane = tid & 63;
  char* ldsP = lds + 32768 + w * 4096;  // per-wave [2 mf][16 q][128 B]
  int bid = blockIdx.x;
  int swz = (bid & 7) * 96 + (bid >> 3);  // XCD-chunked: 3 splits per XCD
  int sp = swz >> 5, h = (swz >> 2) & 7, qb = swz & 3;
  int t0 = (sp * NT) / NSPLIT;
  int t1 = ((sp + 1) * NT) / NSPLIT;      // balanced 20-21 tiles; all splits write
  int cl = lane & 15, rg = lane >> 4;
  int qbase = qb * 128 + w * 32;

  bf16x8 qf[2][4];
  #pragma unroll
  for (int mf = 0; mf < 2; ++mf)
    #pragma unroll
    for (int ks = 0; ks < 4; ++ks)
      qf[mf][ks] = *(const bf16x8*)(Qr + (long)(qbase + mf * 16 + cl) * DIM + h * HD + ks * 32 + rg * 8);

  bf16x8 ones;
  #pragma unroll
  for (int j = 0; j < 8; ++j) ones[j] = (bf16)1.0f;

  f32x4 Oa[2][8] = {};
  f32x4 l_acc[2] = {};
  float m_r[2] = {-1e30f, -1e30f};

  const float sc = 0.08838834764831845f;
  for (int t = t0; t < t1; ++t) {
    int k0 = t * 64;
    __syncthreads();   // all waves done reading previous tile's K/V
    {
      int rK = lane >> 4, gK = lane & 15;
      #pragma unroll
      for (int j = 0; j < 4; ++j) {
        int rb = w * 16 + j * 4;
        int row = rb + rK;
        int gs = gK ^ (row & 7);
        gl_lds16((const char*)(Kr + (long)(k0 + row) * DIM + h * HD) + gs * 16,
                 ldsK + rb * 256);
      }
      int rV = lane >> 3, gV = lane & 7;
      #pragma unroll
      for (int j = 0; j < 4; ++j) {
        int db = w * 32 + j * 8;
        int d = db + rV;
        int gs = gV ^ (d & 7);
        gl_lds16((const char*)(VT + (long)(h * HD + d) * SKP + k0) + gs * 16,
                 ldsV + db * 128);
      }
    }
    __syncthreads();   // staged data visible

    f32x4 sa[2][4] = {};
    #pragma unroll
    for (int ks = 0; ks < 4; ++ks) {
      #pragma unroll
      for (int nf = 0; nf < 4; ++nf) {
        int key = nf * 16 + cl;
        int c = ks * 4 + rg;
        bf16x8 kb = *(const bf16x8*)(ldsK + key * 256 + ((c ^ (key & 7)) * 16));
        sa[0][nf] = __builtin_amdgcn_mfma_f32_16x16x32_bf16(qf[0][ks], kb, sa[0][nf], 0, 0, 0);
        sa[1][nf] = __builtin_amdgcn_mfma_f32_16x16x32_bf16(qf[1][ks], kb, sa[1][nf], 0, 0, 0);
      }
    }

    float bia[4];
    #pragma unroll
    for (int nf = 0; nf < 4; ++nf) bia[nf] = biasA[k0 + nf * 16 + cl];

    #pragma unroll
    for (int mf = 0; mf < 2; ++mf) {
      char* ldsPmf = ldsP + mf * 2048;
      #pragma unroll
      for (int nf = 0; nf < 4; ++nf)
        #pragma unroll
        for (int r = 0; r < 4; ++r) sa[mf][nf][r] = sa[mf][nf][r] * sc + bia[nf];
      // group max (rows rg*4..rg*4+3 share one max): lane-local 16 -> 4-step cl reduce
      float mx = sa[mf][0][0];
      #pragma unroll
      for (int nf = 0; nf < 4; ++nf)
        #pragma unroll
        for (int r = 0; r < 4; ++r) mx = fmaxf(mx, sa[mf][nf][r]);
      mx = fmaxf(mx, __shfl_xor(mx, 1));
      mx = fmaxf(mx, __shfl_xor(mx, 2));
      mx = fmaxf(mx, __shfl_xor(mx, 4));
      mx = fmaxf(mx, __shfl_xor(mx, 8));
      bool grew = mx > m_r[mf] + 6.0f;     // defer-max THR=6; p <= e^6 ok in bf16
      if (__any(grew)) {
        float mn = grew ? mx : m_r[mf];
        float scale = __expf(m_r[mf] - mn);
        m_r[mf] = mn;
        l_acc[mf] *= scale;
        #pragma unroll
        for (int df = 0; df < 8; ++df) Oa[mf][df] *= scale;
      }
      #pragma unroll
      for (int nf = 0; nf < 4; ++nf)
        #pragma unroll
        for (int r = 0; r < 4; ++r) {
          float p = __expf(sa[mf][nf][r] - m_r[mf]);
          int qr = rg * 4 + r;
          int col = nf * 16 + cl;
          int gp = (col >> 3) ^ (qr & 7);
          *(bf16*)(ldsPmf + qr * 128 + gp * 16 + (col & 7) * 2) = (bf16)p;
        }
    }

    // PV + l-sum: vb read once, consumed by both mf; l = MFMA(P, ones)
    #pragma unroll
    for (int ks = 0; ks < 2; ++ks) {
      int c = ks * 4 + rg;
      bf16x8 pa0 = *(const bf16x8*)(ldsP + cl * 128 + ((c ^ (cl & 7)) * 16));
      bf16x8 pa1 = *(const bf16x8*)(ldsP + 2048 + cl * 128 + ((c ^ (cl & 7)) * 16));
      l_acc[0] = __builtin_amdgcn_mfma_f32_16x16x32_bf16(pa0, ones, l_acc[0], 0, 0, 0);
      l_acc[1] = __builtin_amdgcn_mfma_f32_16x16x32_bf16(pa1, ones, l_acc[1], 0, 0, 0);
      #pragma unroll
      for (int df = 0; df < 8; ++df) {
        int d = df * 16 + cl;
        bf16x8 vb = *(const bf16x8*)(ldsV + d * 128 + ((c ^ (d & 7)) * 16));
        Oa[0][df] = __builtin_amdgcn_mfma_f32_16x16x32_bf16(pa0, vb, Oa[0][df], 0, 0, 0);
        Oa[1][df] = __builtin_amdgcn_mfma_f32_16x16x32_bf16(pa1, vb, Oa[1][df], 0, 0, 0);
      }
    }
  }

  long rowb = (long)(sp * HEADS + h) * SQ + qbase;
  #pragma unroll
  for (int mf = 0; mf < 2; ++mf) {
    #pragma unroll
    for (int df = 0; df < 8; ++df)
      #pragma unroll
      for (int r = 0; r < 4; ++r) {
        int qr = mf * 16 + rg * 4 + r;
        Opart[(rowb + qr) * HD + df * 16 + cl] = Oa[mf][df][r];
      }
    if (cl == 0) {
      #pragma unroll
      for (int r = 0; r < 4; ++r) {
        int qr = mf * 16 + rg * 4 + r;
        ml[(rowb + qr) * 2] = m_r[mf];
        ml[(rowb + qr) * 2 + 1] = l_acc[mf][r];
      }
    }
  }
}

__global__ __launch_bounds__(128) void k_combine(const float* __restrict__ Opart,
    const float* __restrict__ ml, bf16* __restrict__ AO) {
  int bid = blockIdx.x;
  int h = bid >> 9, qq = bid & 511;
  int d = threadIdx.x;
  float M = -1e30f;
  #pragma unroll 4
  for (int s2 = 0; s2 < NSPLIT; ++s2) {
    long mi = (long)(s2 * HEADS + h) * SQ + qq;
    M = fmaxf(M, ml[mi * 2]);
  }
  float L = 0.f, acc = 0.f;
  #pragma unroll 4
  for (int s2 = 0; s2 < NSPLIT; ++s2) {
    long mi = (long)(s2 * HEADS + h) * SQ + qq;
    float wgt = __expf(ml[mi * 2] - M);
    L += wgt * ml[mi * 2 + 1];
    acc += wgt * Opart[mi * HD + d];
  }
  AO[(long)qq * DIM + h * HD + d] = (bf16)(acc / L);
}

// ---------------- host ----------------

extern "C" void kernel_launch(void* const* d_in, const int* in_sizes, int n_in,
                              void* d_out, int out_size, void* d_ws, size_t ws_size,
                              hipStream_t stream) {
  const float* x     = (const float*)d_in[0];
  const float* mem   = (const float*)d_in[1];
  const int*   mask  = (const int*)d_in[2];
  const float* cos_q = (const float*)d_in[3];
  const float* sin_q = (const float*)d_in[4];
  const float* cos_k = (const float*)d_in[5];
  const float* sin_k = (const float*)d_in[6];
  const float* Wq    = (const float*)d_in[7];
  const float* bq    = (const float*)d_in[8];
  const float* Wk    = (const float*)d_in[9];
  const float* bk    = (const float*)d_in[10];
  const float* Wv    = (const float*)d_in[11];
  const float* bv    = (const float*)d_in[12];
  const float* Wo    = (const float*)d_in[13];
  const float* bo    = (const float*)d_in[14];
  const float* gq    = (const float*)d_in[15];
  const float* gk    = (const float*)d_in[16];

  char* ws = (char*)d_ws;
  bf16*  memb = (bf16*)(ws + OFF_MEMB);
  bf16*  xb   = (bf16*)(ws + OFF_XB);
  bf16*  WkvB = (bf16*)(ws + OFF_WKV);
  bf16*  WqB  = (bf16*)(ws + OFF_WQ);
  bf16*  WoB  = (bf16*)(ws + OFF_WO);
  float* bKV  = (float*)(ws + OFF_BKV);
  bf16*  Kpre = (bf16*)(ws + OFF_KPRE);
  bf16*  VT   = (bf16*)(ws + OFF_VT);
  float* Qpre = (float*)(ws + OFF_QPRE);
  bf16*  Qr   = (bf16*)(ws + OFF_QR);
  float* biasA= (float*)(ws + OFF_BIAS);
  float* Opart= (float*)(ws + OFF_OP);
  float* mlb  = (float*)(ws + OFF_ML);
  bf16*  AO   = (bf16*)(ws + OFF_AO);

  k_cvt_mem<<<dim3((SKP * DIM / 8 + 255) / 256), dim3(256), 0, stream>>>(mem, memb);
  k_cvt<<<dim3(SQ * DIM / 8 / 256), dim3(256), 0, stream>>>(x, xb, (long)(SQ * DIM / 8));
  k_cvt<<<dim3(DIM * DIM / 8 / 256), dim3(256), 0, stream>>>(Wq, WqB, (long)(DIM * DIM / 8));
  k_cvt<<<dim3(DIM * DIM / 8 / 256), dim3(256), 0, stream>>>(Wo, WoB, (long)(DIM * DIM / 8));
  k_build_wkv<<<dim3(2048 * DIM / 8 / 256), dim3(256), 0, stream>>>(Wk, Wv, bk, bv, WkvB, bKV);
  k_bias<<<dim3((SKP + 255) / 256), dim3(256), 0, stream>>>(mask, biasA);

  k_gemm<0><<<dim3(4 * 8), dim3(256), 0, stream>>>(xb, WqB, bq, 4, 8, Qpre, DIM,
                                                   (bf16*)nullptr, (bf16*)nullptr);
  k_gemm<1><<<dim3(245 * 16), dim3(256), 0, stream>>>(memb, WkvB, bKV, 245, 16,
                                                      (float*)nullptr, 0, Kpre, VT);

  k_fuse_q<<<dim3(SQ), dim3(256), 0, stream>>>(Qpre, Qr, gq, cos_q, sin_q);
  k_fuse_k<<<dim3(SK), dim3(256), 0, stream>>>(Kpre, gk, cos_k, sin_k);

  k_attn<<<dim3(NSPLIT * HEADS * 4), dim3(256), 0, stream>>>(Kpre, VT, Qr, biasA, Opart, mlb);
  k_combine<<<dim3(HEADS * SQ), dim3(128), 0, stream>>>(Opart, mlb, AO);

  k_gemm<0><<<dim3(4 * 8), dim3(256), 0, stream>>>(AO, WoB, bo, 4, 8, (float*)d_out, DIM,
                                                   (bf16*)nullptr, (bf16*)nullptr);
  (void)in_sizes; (void)n_in; (void)out_size; (void)ws_size;
}